// Round 1
// 1103.982 us; speedup vs baseline: 1.2946x; 1.2946x over previous
//
#include <hip/hip_runtime.h>
#include <hip/hip_bf16.h>
#include <math.h>

#define IN_F 512
#define OUT_F 50000
#define BATCH 4096
#define SCALE 30.0f

// margin constants (MARGIN = 0.5)
#define COS_M_ 0.8775825618903728f
#define SIN_M_ 0.479425538604203f
#define TH_   (-0.8775825618903728f)
#define MM_   0.2397127693021015f

typedef __bf16 bf16x8 __attribute__((ext_vector_type(8)));
typedef float f32x4 __attribute__((ext_vector_type(4)));

__device__ __forceinline__ void gl_lds16(const void* g, void* l) {
  __builtin_amdgcn_global_load_lds(
      (const __attribute__((address_space(1))) void*)g,
      (__attribute__((address_space(3))) void*)l,
      16, 0, 0);
}

// ---------------------------------------------------------------------------
// Row L2-normalize fp32 -> bf16.  One block (256 thr) per row of 512 floats.
// ---------------------------------------------------------------------------
__global__ void normalize_rows(const float* __restrict__ x,
                               __bf16* __restrict__ y) {
  const int row = blockIdx.x;
  const int tid = threadIdx.x;
  float2 v = ((const float2*)(x + (size_t)row * IN_F))[tid];
  float ss = v.x * v.x + v.y * v.y;
#pragma unroll
  for (int m = 1; m < 64; m <<= 1) ss += __shfl_xor(ss, m);
  __shared__ float wss[4];
  const int lane = tid & 63, w = tid >> 6;
  if (lane == 0) wss[w] = ss;
  __syncthreads();
  float tot = wss[0] + wss[1] + wss[2] + wss[3];
  float inv = 1.0f / fmaxf(sqrtf(tot), 1e-12f);
  union { __bf16 h[2]; unsigned int u; } p;
  p.h[0] = (__bf16)(v.x * inv);
  p.h[1] = (__bf16)(v.y * inv);
  ((unsigned int*)y)[(size_t)row * (IN_F / 2) + tid] = p.u;
}

// ---------------------------------------------------------------------------
// Fused GEMM + ArcFace margin + scale + store + per-row sum(exp).
// C[b][c] = dot(An[b,:], Wn[c,:])  -- NT gemm, both K-contiguous.
// 128x128 tile, BK=32, 256 threads = 4 waves (2x2), 4x4 MFMA 16x16x32 / wave.
//
// B-row remap: LDS B slot p (within a 64-col wave band, p = nt*16 + fr) holds
// the Wn row for class  col0 + band*64 + fr*4 + nt.  Then a thread's 4 nt
// accumulators are 4 CONSECUTIVE output columns -> one float4 NT store per
// (mt,rg); each store instr covers 4 rows x 256B contiguous (full lines, no
// write-RMW fetch).
// ---------------------------------------------------------------------------
__global__ __launch_bounds__(256, 2) void arc_gemm(
    const __bf16* __restrict__ A,   // [BATCH, IN_F] normalized bf16
    const __bf16* __restrict__ Wn,  // [OUT_F, IN_F] normalized bf16
    const int* __restrict__ label,
    float* __restrict__ out,        // [BATCH, OUT_F]
    float* __restrict__ sumexp)     // [BATCH]
{
  __shared__ __align__(16) __bf16 lA[128 * 32];
  __shared__ __align__(16) __bf16 lB[128 * 32];
  __shared__ int lbl[128];

  const int tid = threadIdx.x;
  const int lane = tid & 63;
  const int wv = tid >> 6;
  const int wm = wv >> 1;
  const int wn = wv & 1;
  const int bm = blockIdx.x;   // row-block on FAST axis: consecutive blocks
  const int bn = blockIdx.y;   // share the same 131KB Wn band (L2/L3 reuse)
  const int row0 = bm * 128;
  const int col0 = bn * 128;

  if (tid < 128) lbl[tid] = label[row0 + tid];

  // staging: chunk c (16B) -> lds row c>>2, k-offset (c&3)*8 elems.
  // per thread chunks c0 = tid, c1 = tid+256 (512 chunks = 128x32 bf16 tile)
  const int c0 = tid, c1 = tid + 256;
  const int ar0 = c0 >> 2, ak0 = (c0 & 3) * 8;
  const int ar1 = c1 >> 2, ak1 = (c1 & 3) * 8;
  const __bf16* agp0 = A + (size_t)(row0 + ar0) * IN_F + ak0;
  const __bf16* agp1 = A + (size_t)(row0 + ar1) * IN_F + ak1;
  // B-row remap: slot r -> class offset (r&64) + (r&15)*4 + ((r>>4)&3)
  const int rm0 = (ar0 & 64) + ((ar0 & 15) << 2) + ((ar0 >> 4) & 3);
  const int rm1 = (ar1 & 64) + ((ar1 & 15) << 2) + ((ar1 >> 4) & 3);
  int wrow0 = col0 + rm0; if (wrow0 >= OUT_F) wrow0 = OUT_F - 1;  // clamp OOB
  int wrow1 = col0 + rm1; if (wrow1 >= OUT_F) wrow1 = OUT_F - 1;
  const __bf16* wgp0 = Wn + (size_t)wrow0 * IN_F + ak0;
  const __bf16* wgp1 = Wn + (size_t)wrow1 * IN_F + ak1;
  __bf16* lA0 = lA + c0 * 8;
  __bf16* lA1 = lA + c1 * 8;
  __bf16* lB0 = lB + c0 * 8;
  __bf16* lB1 = lB + c1 * 8;

  f32x4 acc[4][4] = {};  // [mt][nt]

  const int fr = lane & 15;  // row (A) / B-slot within 16
  const int fq = lane >> 4;  // quad -> k offset fq*8

  for (int kt = 0; kt < IN_F / 32; ++kt) {
    __syncthreads();  // prev iter's LDS reads done before overwrite
    const int ko = kt * 32;
    gl_lds16(agp0 + ko, lA0);
    gl_lds16(agp1 + ko, lA1);
    gl_lds16(wgp0 + ko, lB0);
    gl_lds16(wgp1 + ko, lB1);
    __syncthreads();  // staging drained (compiler emits vmcnt(0) here)

    bf16x8 af[4], bfr[4];
#pragma unroll
    for (int mt = 0; mt < 4; ++mt)
      af[mt] = *(const bf16x8*)&lA[(wm * 64 + mt * 16 + fr) * 32 + fq * 8];
#pragma unroll
    for (int nt = 0; nt < 4; ++nt)
      bfr[nt] = *(const bf16x8*)&lB[(wn * 64 + nt * 16 + fr) * 32 + fq * 8];
#pragma unroll
    for (int mt = 0; mt < 4; ++mt)
#pragma unroll
      for (int nt = 0; nt < 4; ++nt)
        acc[mt][nt] = __builtin_amdgcn_mfma_f32_16x16x32_bf16(
            af[mt], bfr[nt], acc[mt][nt], 0, 0, 0);
  }

  // Epilogue: margin, scale, NT float4 store, per-row partial sum(exp).
  // C/D layout: tile-pos = lane&15 (fr), row = (lane>>4)*4 + reg [m89-verified]
  // With the B remap, acc[mt][nt][rg] is class gc0 + nt where
  // gc0 = col0 + wn*64 + fr*4  (4 consecutive classes per thread).
  float rsum[4][4];
#pragma unroll
  for (int mt = 0; mt < 4; ++mt)
#pragma unroll
    for (int rg = 0; rg < 4; ++rg) rsum[mt][rg] = 0.0f;

  const int gc0 = col0 + wn * 64 + fr * 4;   // 16B-aligned, +3 stays in-bounds
                                             // iff gc0 < OUT_F (OUT_F%4==0)
#pragma unroll
  for (int mt = 0; mt < 4; ++mt) {
    const int lrow_base = wm * 64 + mt * 16 + fq * 4;
#pragma unroll
    for (int rg = 0; rg < 4; ++rg) {
      const int lrow = lrow_base + rg;
      const int tlbl = lbl[lrow];
      const size_t orow = (size_t)(row0 + lrow) * OUT_F;
      f32x4 ov;
      float rs = 0.0f;
#pragma unroll
      for (int nt = 0; nt < 4; ++nt) {
        float c = acc[mt][nt][rg];
        float s2 = 1.0f - c * c;
        s2 = s2 > 0.0f ? s2 : 0.0f;
        float phi = c * COS_M_ - sqrtf(s2) * SIN_M_;
        phi = (c > TH_) ? phi : (c - MM_);
        float o = SCALE * (((gc0 + nt) == tlbl) ? phi : c);
        ov[nt] = o;
        rs += __expf(o);  // |o|<=30: no overflow, no max needed
      }
      if (gc0 < OUT_F) {
        __builtin_nontemporal_store(ov, (f32x4*)(out + orow + gc0));
        rsum[mt][rg] += rs;
      }
    }
  }

  // reduce each row-partial across the 16 lanes of a quad, then atomicAdd
#pragma unroll
  for (int mt = 0; mt < 4; ++mt)
#pragma unroll
    for (int rg = 0; rg < 4; ++rg) {
      float v = rsum[mt][rg];
      v += __shfl_xor(v, 1);
      v += __shfl_xor(v, 2);
      v += __shfl_xor(v, 4);
      v += __shfl_xor(v, 8);
      if (fr == 0)
        atomicAdd(&sumexp[row0 + wm * 64 + mt * 16 + fq * 4 + rg], v);
    }
}

// ---------------------------------------------------------------------------
// loss = mean_b [ log(sumexp[b]) - out[b, label[b]] ]   (single block)
// ---------------------------------------------------------------------------
__global__ void loss_kernel(const float* __restrict__ out,
                            const float* __restrict__ sumexp,
                            const int* __restrict__ label,
                            float* __restrict__ loss) {
  const int tid = threadIdx.x;
  float s = 0.0f;
  for (int b = tid; b < BATCH; b += 256) {
    float t = out[(size_t)b * OUT_F + label[b]];
    s += logf(sumexp[b]) - t;
  }
  __shared__ float red[256];
  red[tid] = s;
  __syncthreads();
  for (int st = 128; st > 0; st >>= 1) {
    if (tid < st) red[tid] += red[tid + st];
    __syncthreads();
  }
  if (tid == 0) loss[0] = red[0] / (float)BATCH;
}

// ---------------------------------------------------------------------------
extern "C" void kernel_launch(void* const* d_in, const int* in_sizes, int n_in,
                              void* d_out, int out_size, void* d_ws, size_t ws_size,
                              hipStream_t stream) {
  const float* input  = (const float*)d_in[0];
  const int*   label  = (const int*)d_in[1];
  const float* weight = (const float*)d_in[2];
  float* out  = (float*)d_out;
  float* loss = out + (size_t)BATCH * OUT_F;

  char* ws = (char*)d_ws;
  __bf16* An = (__bf16*)ws;                                     // 4 MiB
  __bf16* Wn = (__bf16*)(ws + (size_t)BATCH * IN_F * 2);        // 51.2 MB
  float* sumexp = (float*)(ws + (size_t)BATCH * IN_F * 2 +
                           (size_t)OUT_F * IN_F * 2);           // 16 KB

  hipMemsetAsync(sumexp, 0, BATCH * sizeof(float), stream);     // ws is poisoned
  normalize_rows<<<BATCH, 256, 0, stream>>>(input, An);
  normalize_rows<<<OUT_F, 256, 0, stream>>>(weight, Wn);
  dim3 grid(BATCH / 128, (OUT_F + 127) / 128);  // bm fast: Wn-band reuse
  arc_gemm<<<grid, 256, 0, stream>>>(An, Wn, label, out, sumexp);
  loss_kernel<<<1, 256, 0, stream>>>(out, sumexp, label, loss);
}